// Round 1
// baseline (54.155 us; speedup 1.0000x reference)
//
#include <hip/hip_runtime.h>

#define LN_EPS 1e-5f

// out[b,n,f,e] = xn[b,n,f] * w[f,e] + (b[f,e] + emb[f,e])
// xn = LayerNorm over F=64 of x[b,n,:]
// B=4, N=4096, F=64, E=64 -> rows = 16384, 4096 fp32 outputs per row.

__global__ __launch_bounds__(256) void pte_kernel(
    const float* __restrict__ x,      // [rows, 64]
    const float* __restrict__ gamma,  // [64]
    const float* __restrict__ beta,   // [64]
    const float* __restrict__ w,      // [64, 64]
    const float* __restrict__ pb,     // [64, 64]
    const float* __restrict__ emb,    // [64, 64]
    float* __restrict__ out)          // [rows, 4096]
{
    const int row = blockIdx.x;
    const int tid = threadIdx.x;

    __shared__ float xn_s[64];

    // --- Wave 0: LayerNorm of the 64-wide feature row (1 lane per feature) ---
    if (tid < 64) {
        float v = x[(size_t)row * 64 + tid];

        // mean: butterfly sum across the full 64-lane wave
        float s = v;
        #pragma unroll
        for (int m = 1; m < 64; m <<= 1) s += __shfl_xor(s, m, 64);
        float mu = s * (1.0f / 64.0f);

        float d = v - mu;
        float s2 = d * d;
        #pragma unroll
        for (int m = 1; m < 64; m <<= 1) s2 += __shfl_xor(s2, m, 64);
        float inv = rsqrtf(s2 * (1.0f / 64.0f) + LN_EPS);

        xn_s[tid] = d * inv * gamma[tid] + beta[tid];
    }
    __syncthreads();

    // --- All 256 threads: write the 4096-float output row as 1024 float4s ---
    const float4* __restrict__ w4 = (const float4*)w;
    const float4* __restrict__ b4 = (const float4*)pb;
    const float4* __restrict__ e4 = (const float4*)emb;
    float4* __restrict__ o4 = (float4*)(out + (size_t)row * 4096);

    #pragma unroll
    for (int i = 0; i < 4; ++i) {
        int idx = i * 256 + tid;       // float4 index in [0, 1024): flat = 4*idx
        int f = idx >> 4;              // 64 floats (16 float4) per feature
        float xn = xn_s[f];            // broadcast within 16-lane groups
        float4 wv = w4[idx];
        float4 bv = b4[idx];
        float4 ev = e4[idx];
        float4 r;
        r.x = fmaf(xn, wv.x, bv.x + ev.x);
        r.y = fmaf(xn, wv.y, bv.y + ev.y);
        r.z = fmaf(xn, wv.z, bv.z + ev.z);
        r.w = fmaf(xn, wv.w, bv.w + ev.w);
        o4[idx] = r;
    }
}

extern "C" void kernel_launch(void* const* d_in, const int* in_sizes, int n_in,
                              void* d_out, int out_size, void* d_ws, size_t ws_size,
                              hipStream_t stream) {
    const float* x     = (const float*)d_in[0];  // [4,4096,64]
    const float* gamma = (const float*)d_in[1];  // [64]
    const float* beta  = (const float*)d_in[2];  // [64]
    const float* w     = (const float*)d_in[3];  // [64,64]
    const float* pb    = (const float*)d_in[4];  // [64,64]
    const float* emb   = (const float*)d_in[5];  // [64,64]
    float* out = (float*)d_out;

    const int rows = 4 * 4096;  // B * N
    pte_kernel<<<rows, 256, 0, stream>>>(x, gamma, beta, w, pb, emb, out);
}